// Round 8
// baseline (489.682 us; speedup 1.0000x reference)
//
#include <hip/hip_runtime.h>

#define NROWS 8
#define NBLK  1024            // NBLK * NROWS = 8192 rows; 4 blocks/CU resident
#define R2F 0.70710678118654752f
#define TWO_PI 6.28318530717958648f

// +2 complex every 32: breaks pow2 strides, preserves 16B alignment
#define CIDX(c) ((c) + (((c) >> 5) << 1))

typedef float2 cf;

__device__ __forceinline__ cf cadd(cf a, cf b){ return make_float2(a.x+b.x, a.y+b.y); }
__device__ __forceinline__ cf csub(cf a, cf b){ return make_float2(a.x-b.x, a.y-b.y); }
__device__ __forceinline__ cf cmul(cf a, cf b){ return make_float2(a.x*b.x - a.y*b.y, a.x*b.y + a.y*b.x); }
__device__ __forceinline__ cf cmulNI(cf a){ return make_float2(a.y, -a.x); }                 // * (-i)
__device__ __forceinline__ cf cW8(cf a){ return make_float2(R2F*(a.x + a.y), R2F*(a.y - a.x)); }   // * W8^1
__device__ __forceinline__ cf cW83(cf a){ return make_float2(R2F*(a.y - a.x), -R2F*(a.x + a.y)); } // * W8^3

// in-register 8-point DFT, natural in / natural out (v[p] = bin p)
__device__ __forceinline__ void fft8(cf v[8]) {
    cf s0=cadd(v[0],v[4]), s1=cadd(v[1],v[5]), s2=cadd(v[2],v[6]), s3=cadd(v[3],v[7]);
    cf d0=csub(v[0],v[4]), d1=csub(v[1],v[5]), d2=csub(v[2],v[6]), d3=csub(v[3],v[7]);
    cf t1=cW8(d1), t2=cmulNI(d2), t3=cW83(d3);
    cf ss0=cadd(s0,s2), ss1=cadd(s1,s3), sd0=csub(s0,s2), sd1=csub(s1,s3);
    v[0]=cadd(ss0,ss1);
    v[2]=make_float2(sd0.x+sd1.y, sd0.y-sd1.x);
    v[4]=csub(ss0,ss1);
    v[6]=make_float2(sd0.x-sd1.y, sd0.y+sd1.x);
    cf tt0=cadd(d0,t2), tt1=cadd(t1,t3), td0=csub(d0,t2), td1=csub(t1,t3);
    v[1]=cadd(tt0,tt1);
    v[3]=make_float2(td0.x+td1.y, td0.y-td1.x);
    v[5]=csub(tt0,tt1);
    v[7]=make_float2(td0.x-td1.y, td0.y+td1.x);
}

// 64-lane sum via DPP; valid in lane 63
__device__ __forceinline__ float wred(float x) {
    x += __int_as_float(__builtin_amdgcn_update_dpp(0, __float_as_int(x), 0x111, 0xf, 0xf, false));
    x += __int_as_float(__builtin_amdgcn_update_dpp(0, __float_as_int(x), 0x112, 0xf, 0xf, false));
    x += __int_as_float(__builtin_amdgcn_update_dpp(0, __float_as_int(x), 0x114, 0xf, 0xf, false));
    x += __int_as_float(__builtin_amdgcn_update_dpp(0, __float_as_int(x), 0x118, 0xf, 0xf, false));
    x += __int_as_float(__builtin_amdgcn_update_dpp(0, __float_as_int(x), 0x142, 0xa, 0xf, false));
    x += __int_as_float(__builtin_amdgcn_update_dpp(0, __float_as_int(x), 0x143, 0xc, 0xf, false));
    return x;
}

// LDS-only barrier: register prefetch loads stay in flight (vmcnt untouched)
__device__ __forceinline__ void bar_lds() {
    asm volatile("s_waitcnt lgkmcnt(0)" ::: "memory");
    __builtin_amdgcn_s_barrier();
}

__global__ __launch_bounds__(512, 8)
void fftmlp_r8p(const float* __restrict__ x, const float* __restrict__ w1,
                const float* __restrict__ w2, float* __restrict__ out) {
    __shared__ __align__(16) cf buf[CIDX(4095) + 1];
    __shared__ float sred[80];
    const int t  = threadIdx.x;
    const int b0 = blockIdx.x * NROWS;
    const cf* __restrict__ w1c = (const cf*)w1;
    const cf* __restrict__ w2c = (const cf*)w2;
    const cf* __restrict__ xc  = (const cf*)x;
    float sn, cs;

    // ---- prefetch row 0 into registers ----
    cf P[8];
    {
        const cf* __restrict__ xr = xc + (size_t)b0 * 4096;
        #pragma unroll
        for (int k = 0; k < 8; ++k) P[k] = xr[t + 512*k];
    }

    for (int rr = 0; rr < NROWS; ++rr) {
        // ---- pass 0: consume P * w1, fft8 over stride 512, twiddle W_4096^t ----
        {
            cf v[8];
            #pragma unroll
            for (int k = 0; k < 8; ++k)
                v[k] = cmul(P[k], w1c[t + 512*k]);
            fft8(v);
            __sincosf(-TWO_PI * (float)t * (1.0f/4096.0f), &sn, &cs);
            cf w = make_float2(cs, sn);
            buf[CIDX(t)] = v[0];
            cf tw = w;
            #pragma unroll
            for (int p = 1; p < 8; ++p) {
                buf[CIDX(t + 512*p)] = cmul(v[p], tw);
                tw = cmul(tw, w);
            }
        }
        // ---- issue next row's prefetch; stays in flight across all barriers ----
        if (rr + 1 < NROWS) {
            const cf* __restrict__ xn = xc + (size_t)(b0 + rr + 1) * 4096;
            #pragma unroll
            for (int k = 0; k < 8; ++k) P[k] = xn[t + 512*k];
        }
        bar_lds();

        // ---- pass 1: within 512-blocks, stride 64, twiddle W_512^(t&63) ----
        {
            const int base = ((t >> 6) << 9) | (t & 63);
            cf v[8];
            #pragma unroll
            for (int k = 0; k < 8; ++k) v[k] = buf[CIDX(base + 64*k)];
            fft8(v);
            __sincosf(-TWO_PI * (float)(t & 63) * (1.0f/512.0f), &sn, &cs);
            cf w = make_float2(cs, sn);
            buf[CIDX(base)] = v[0];
            cf tw = w;
            #pragma unroll
            for (int p = 1; p < 8; ++p) {
                buf[CIDX(base + 64*p)] = cmul(v[p], tw);
                tw = cmul(tw, w);
            }
        }
        bar_lds();

        // ---- pass 2: within 64-blocks, stride 8, twiddle W_64^(t&7) ----
        {
            const int base = ((t >> 3) << 6) | (t & 7);
            cf v[8];
            #pragma unroll
            for (int k = 0; k < 8; ++k) v[k] = buf[CIDX(base + 8*k)];
            fft8(v);
            __sincosf(-TWO_PI * (float)(t & 7) * (1.0f/64.0f), &sn, &cs);
            cf w = make_float2(cs, sn);
            buf[CIDX(base)] = v[0];
            cf tw = w;
            #pragma unroll
            for (int p = 1; p < 8; ++p) {
                buf[CIDX(base + 8*p)] = cmul(v[p], tw);
                tw = cmul(tw, w);
            }
        }
        bar_lds();

        // ---- final: contiguous 8-group; only bins n0 (p=0), n0+512 (p=1) needed ----
        float rv[10];
        {
            cf z[8];
            const float4* __restrict__ lp = reinterpret_cast<const float4*>(&buf[CIDX(8*t)]);
            #pragma unroll
            for (int j2 = 0; j2 < 4; ++j2) {
                float4 q = lp[j2];
                z[2*j2]   = make_float2(q.x, q.y);
                z[2*j2+1] = make_float2(q.z, q.w);
            }
            cf F0 = cadd(cadd(cadd(z[0],z[1]), cadd(z[2],z[3])),
                         cadd(cadd(z[4],z[5]), cadd(z[6],z[7])));
            cf d0=csub(z[0],z[4]), d1=csub(z[1],z[5]), d2=csub(z[2],z[6]), d3=csub(z[3],z[7]);
            cf F1 = cadd(cadd(d0, cW8(d1)), cadd(cmulNI(d2), cW83(d3)));

            const int n0 = ((t & 7) << 6) | (t & 56) | ((t >> 6) & 7);  // octal-reverse
            cf h0 = make_float2(fmaxf(F0.x, 0.f), fmaxf(F0.y, 0.f));
            cf h1 = make_float2(fmaxf(F1.x, 0.f), fmaxf(F1.y, 0.f));
            cf P0 = cmul(h0, w2c[n0]);
            cf P1 = cmul(h1, w2c[512 + n0]);
            cf E = cadd(P0, P1), O = csub(P0, P1);   // bin n0+512: W_1024^{512k}=(-1)^k
            __sincosf(-TWO_PI * (float)n0 * (1.0f/1024.0f), &sn, &cs);
            cf W1v = make_float2(cs, sn);
            cf W2v = cmul(W1v, W1v);
            cf W3v = cmul(W2v, W1v);
            cf W4v = cmul(W2v, W2v);
            cf a1 = cmul(O, W1v);
            cf a2 = cmul(E, W2v);
            cf a3 = cmul(O, W3v);
            cf a4 = cmul(E, W4v);
            rv[0]=E.x;  rv[1]=E.y;  rv[2]=a1.x; rv[3]=a1.y; rv[4]=a2.x;
            rv[5]=a2.y; rv[6]=a3.x; rv[7]=a3.y; rv[8]=a4.x; rv[9]=a4.y;
        }

        // ---- reduce 512 threads (8 waves) -> 10 floats ----
        #pragma unroll
        for (int i = 0; i < 10; ++i) rv[i] = wred(rv[i]);
        const int lane = t & 63, wv = t >> 6;
        if (lane == 63) {
            #pragma unroll
            for (int i = 0; i < 10; ++i) sred[wv*10 + i] = rv[i];
        }
        bar_lds();   // sred visible; all final buf-reads done -> next pass0 may write
        if (t < 10) {
            float s = sred[t];
            #pragma unroll
            for (int w = 1; w < 8; ++w) s += sred[w*10 + t];
            out[(b0 + rr)*10 + t] = s;
        }
    }
}

extern "C" void kernel_launch(void* const* d_in, const int* in_sizes, int n_in,
                              void* d_out, int out_size, void* d_ws, size_t ws_size,
                              hipStream_t stream) {
    const float* x  = (const float*)d_in[0];
    const float* w1 = (const float*)d_in[1];
    const float* w2 = (const float*)d_in[2];
    float* out = (float*)d_out;
    fftmlp_r8p<<<NBLK, 512, 0, stream>>>(x, w1, w2, out);
}

// Round 9
// 111.329 us; speedup vs baseline: 4.3985x; 4.3985x over previous
//
#include <hip/hip_runtime.h>
#include <stdint.h>

#define NROWS 8
#define NBLK  1024            // NBLK * NROWS = 8192 rows; 2 blocks/CU resident
#define R2F 0.70710678118654752f
#define TWO_PI 6.28318530717958648f

// +2 complex every 32: breaks pow2 strides, preserves 16B alignment
#define CIDX(c) ((c) + (((c) >> 5) << 1))

typedef float2 cf;

__device__ __forceinline__ cf cadd(cf a, cf b){ return make_float2(a.x+b.x, a.y+b.y); }
__device__ __forceinline__ cf csub(cf a, cf b){ return make_float2(a.x-b.x, a.y-b.y); }
__device__ __forceinline__ cf cmul(cf a, cf b){ return make_float2(a.x*b.x - a.y*b.y, a.x*b.y + a.y*b.x); }
__device__ __forceinline__ cf cmulNI(cf a){ return make_float2(a.y, -a.x); }                 // * (-i)
__device__ __forceinline__ cf cW8(cf a){ return make_float2(R2F*(a.x + a.y), R2F*(a.y - a.x)); }   // * W8^1
__device__ __forceinline__ cf cW83(cf a){ return make_float2(R2F*(a.y - a.x), -R2F*(a.x + a.y)); } // * W8^3

// in-register 8-point DFT, natural in / natural out (v[p] = bin p)
__device__ __forceinline__ void fft8(cf v[8]) {
    cf s0=cadd(v[0],v[4]), s1=cadd(v[1],v[5]), s2=cadd(v[2],v[6]), s3=cadd(v[3],v[7]);
    cf d0=csub(v[0],v[4]), d1=csub(v[1],v[5]), d2=csub(v[2],v[6]), d3=csub(v[3],v[7]);
    cf t1=cW8(d1), t2=cmulNI(d2), t3=cW83(d3);
    cf ss0=cadd(s0,s2), ss1=cadd(s1,s3), sd0=csub(s0,s2), sd1=csub(s1,s3);
    v[0]=cadd(ss0,ss1);
    v[2]=make_float2(sd0.x+sd1.y, sd0.y-sd1.x);
    v[4]=csub(ss0,ss1);
    v[6]=make_float2(sd0.x-sd1.y, sd0.y+sd1.x);
    cf tt0=cadd(d0,t2), tt1=cadd(t1,t3), td0=csub(d0,t2), td1=csub(t1,t3);
    v[1]=cadd(tt0,tt1);
    v[3]=make_float2(td0.x+td1.y, td0.y-td1.x);
    v[5]=csub(tt0,tt1);
    v[7]=make_float2(td0.x-td1.y, td0.y+td1.x);
}

// 64-lane sum via DPP; valid in lane 63
__device__ __forceinline__ float wred(float x) {
    x += __int_as_float(__builtin_amdgcn_update_dpp(0, __float_as_int(x), 0x111, 0xf, 0xf, false));
    x += __int_as_float(__builtin_amdgcn_update_dpp(0, __float_as_int(x), 0x112, 0xf, 0xf, false));
    x += __int_as_float(__builtin_amdgcn_update_dpp(0, __float_as_int(x), 0x114, 0xf, 0xf, false));
    x += __int_as_float(__builtin_amdgcn_update_dpp(0, __float_as_int(x), 0x118, 0xf, 0xf, false));
    x += __int_as_float(__builtin_amdgcn_update_dpp(0, __float_as_int(x), 0x142, 0xa, 0xf, false));
    x += __int_as_float(__builtin_amdgcn_update_dpp(0, __float_as_int(x), 0x143, 0xc, 0xf, false));
    return x;
}

// LDS-only barrier: in-flight global_load_lds survives (vmcnt untouched)
__device__ __forceinline__ void bar_lds() {
    asm volatile("s_waitcnt lgkmcnt(0)" ::: "memory");
    __builtin_amdgcn_s_barrier();
}
// full drain: staged row landed in LDS
__device__ __forceinline__ void bar_vm() {
    asm volatile("s_waitcnt vmcnt(0) lgkmcnt(0)" ::: "memory");
    __builtin_amdgcn_s_barrier();
}

// stream one 32 KB x-row into linear LDS stage; zero VGPR cost.
// call j: wave w covers bytes [j*8192 + w*1024, +1024)
__device__ __forceinline__ void stage_row(const char* __restrict__ xrow,
                                          char* stage, int t) {
    const int lane  = t & 63;
    const int wbase = (t >> 6) * 1024;           // wave-uniform
    const char* g = xrow + wbase + lane * 16;
    char* l = stage + wbase;                      // HW adds lane*16
    #pragma unroll
    for (int j = 0; j < 4; ++j) {
        __builtin_amdgcn_global_load_lds(
            (const __attribute__((address_space(1))) uint32_t*)(g + j * 8192),
            (__attribute__((address_space(3))) uint32_t*)(l + j * 8192),
            16, 0, 0);
    }
}

__global__ __launch_bounds__(512, 4)
void fftmlp_r8s(const float* __restrict__ x, const float* __restrict__ w1,
                const float* __restrict__ w2, float* __restrict__ out) {
    __shared__ __align__(16) cf stage[4096];        // 32 KB linear (gload_lds dest)
    __shared__ __align__(16) cf buf[CIDX(4095) + 1];// ~34.8 KB padded work
    __shared__ float sred[80];
    const int t  = threadIdx.x;
    const int b0 = blockIdx.x * NROWS;
    const cf* __restrict__ w1c = (const cf*)w1;
    const cf* __restrict__ w2c = (const cf*)w2;
    const cf* __restrict__ xc  = (const cf*)x;

    // stage row 0, wait for it
    stage_row((const char*)(xc + (size_t)b0 * 4096), (char*)stage, t);
    bar_vm();

    for (int rr = 0; rr < NROWS; ++rr) {
        // launder t: makes the body loop-variant so LICM can't hoist
        // sincos/address chains into long-lived registers
        int tt = t;
        asm volatile("" : "+v"(tt));
        float sn, cs;

        // ---- pass 0: stage (LDS) x w1 (L2), fft8 over stride 512, twiddle ----
        {
            cf v[8];
            #pragma unroll
            for (int k = 0; k < 8; ++k)
                v[k] = cmul(stage[tt + 512*k], w1c[tt + 512*k]);
            fft8(v);
            __sincosf(-TWO_PI * (float)tt * (1.0f/4096.0f), &sn, &cs);
            cf w = make_float2(cs, sn);
            buf[CIDX(tt)] = v[0];
            cf tw = w;
            #pragma unroll
            for (int p = 1; p < 8; ++p) {
                buf[CIDX(tt + 512*p)] = cmul(v[p], tw);
                tw = cmul(tw, w);
            }
        }
        bar_lds();   // all waves done reading stage + buf writes visible

        // ---- issue next row's DMA; stays in flight across pass1/2/final ----
        if (rr + 1 < NROWS)
            stage_row((const char*)(xc + (size_t)(b0 + rr + 1) * 4096),
                      (char*)stage, t);

        // ---- pass 1: within 512-blocks, stride 64, twiddle W_512^(tt&63) ----
        {
            const int base = ((tt >> 6) << 9) | (tt & 63);
            cf v[8];
            #pragma unroll
            for (int k = 0; k < 8; ++k) v[k] = buf[CIDX(base + 64*k)];
            fft8(v);
            __sincosf(-TWO_PI * (float)(tt & 63) * (1.0f/512.0f), &sn, &cs);
            cf w = make_float2(cs, sn);
            buf[CIDX(base)] = v[0];
            cf tw = w;
            #pragma unroll
            for (int p = 1; p < 8; ++p) {
                buf[CIDX(base + 64*p)] = cmul(v[p], tw);
                tw = cmul(tw, w);
            }
        }
        bar_lds();

        // ---- pass 2: within 64-blocks, stride 8, twiddle W_64^(tt&7) ----
        {
            const int base = ((tt >> 3) << 6) | (tt & 7);
            cf v[8];
            #pragma unroll
            for (int k = 0; k < 8; ++k) v[k] = buf[CIDX(base + 8*k)];
            fft8(v);
            __sincosf(-TWO_PI * (float)(tt & 7) * (1.0f/64.0f), &sn, &cs);
            cf w = make_float2(cs, sn);
            buf[CIDX(base)] = v[0];
            cf tw = w;
            #pragma unroll
            for (int p = 1; p < 8; ++p) {
                buf[CIDX(base + 8*p)] = cmul(v[p], tw);
                tw = cmul(tw, w);
            }
        }
        bar_lds();

        // ---- final: contiguous 8-group; only bins n0 (p=0), n0+512 (p=1) needed ----
        float rv[10];
        {
            cf z[8];
            const float4* __restrict__ lp = reinterpret_cast<const float4*>(&buf[CIDX(8*tt)]);
            #pragma unroll
            for (int j2 = 0; j2 < 4; ++j2) {
                float4 q = lp[j2];
                z[2*j2]   = make_float2(q.x, q.y);
                z[2*j2+1] = make_float2(q.z, q.w);
            }
            cf F0 = cadd(cadd(cadd(z[0],z[1]), cadd(z[2],z[3])),
                         cadd(cadd(z[4],z[5]), cadd(z[6],z[7])));
            cf d0=csub(z[0],z[4]), d1=csub(z[1],z[5]), d2=csub(z[2],z[6]), d3=csub(z[3],z[7]);
            cf F1 = cadd(cadd(d0, cW8(d1)), cadd(cmulNI(d2), cW83(d3)));

            const int n0 = ((tt & 7) << 6) | (tt & 56) | ((tt >> 6) & 7);  // octal-reverse
            cf h0 = make_float2(fmaxf(F0.x, 0.f), fmaxf(F0.y, 0.f));
            cf h1 = make_float2(fmaxf(F1.x, 0.f), fmaxf(F1.y, 0.f));
            cf P0 = cmul(h0, w2c[n0]);
            cf P1 = cmul(h1, w2c[512 + n0]);
            cf E = cadd(P0, P1), O = csub(P0, P1);   // bin n0+512: W_1024^{512k}=(-1)^k
            __sincosf(-TWO_PI * (float)n0 * (1.0f/1024.0f), &sn, &cs);
            cf W1v = make_float2(cs, sn);
            cf W2v = cmul(W1v, W1v);
            cf W3v = cmul(W2v, W1v);
            cf W4v = cmul(W2v, W2v);
            cf a1 = cmul(O, W1v);
            cf a2 = cmul(E, W2v);
            cf a3 = cmul(O, W3v);
            cf a4 = cmul(E, W4v);
            rv[0]=E.x;  rv[1]=E.y;  rv[2]=a1.x; rv[3]=a1.y; rv[4]=a2.x;
            rv[5]=a2.y; rv[6]=a3.x; rv[7]=a3.y; rv[8]=a4.x; rv[9]=a4.y;
        }

        // ---- reduce 512 threads (8 waves) -> 10 floats ----
        #pragma unroll
        for (int i = 0; i < 10; ++i) rv[i] = wred(rv[i]);
        const int lane = t & 63, wv = t >> 6;
        if (lane == 63) {
            #pragma unroll
            for (int i = 0; i < 10; ++i) sred[wv*10 + i] = rv[i];
        }
        bar_lds();   // sred visible; final buf-reads done -> next pass0 may write buf
        if (t < 10) {
            float s = sred[t];
            #pragma unroll
            for (int w = 1; w < 8; ++w) s += sred[w*10 + t];
            out[(b0 + rr)*10 + t] = s;
        }
        bar_vm();    // next row's stage landed; sred consumed before next row's writes
    }
}

extern "C" void kernel_launch(void* const* d_in, const int* in_sizes, int n_in,
                              void* d_out, int out_size, void* d_ws, size_t ws_size,
                              hipStream_t stream) {
    const float* x  = (const float*)d_in[0];
    const float* w1 = (const float*)d_in[1];
    const float* w2 = (const float*)d_in[2];
    float* out = (float*)d_out;
    fftmlp_r8s<<<NBLK, 512, 0, stream>>>(x, w1, w2, out);
}

// Round 10
// 78.965 us; speedup vs baseline: 6.2013x; 1.4099x over previous
//
#include <hip/hip_runtime.h>

#define NBLK 8192
#define C1f 0.92387953251128674f
#define S1f 0.38268343236508978f
#define R2f 0.70710678118654752f
#define TWO_PI 6.28318530717958648f

// bank swizzle: XOR cf-index bits [3:1] with bits [6:4]. Involution on 0..4095.
// Verified: pass-A b64 writes 4 lanes/bank-pair, pass-B b64 4/pair,
// final b128 8 lanes/4-bank-group -> all patterns conflict-optimal.
#define SIDX(c) ((c) ^ ((((c) >> 4) & 7) << 1))

typedef float2 cf;

__device__ __forceinline__ cf cadd(cf a, cf b){ return make_float2(a.x+b.x, a.y+b.y); }
__device__ __forceinline__ cf csub(cf a, cf b){ return make_float2(a.x-b.x, a.y-b.y); }
__device__ __forceinline__ cf cmul(cf a, cf b){ return make_float2(a.x*b.x - a.y*b.y, a.x*b.y + a.y*b.x); }
__device__ __forceinline__ cf cmulNI(cf a){ return make_float2(a.y, -a.x); }              // * (-i)
__device__ __forceinline__ cf cW1(cf a){ return make_float2(C1f*a.x + S1f*a.y, C1f*a.y - S1f*a.x); }  // * W16^1
__device__ __forceinline__ cf cW2(cf a){ return make_float2(R2f*(a.x + a.y), R2f*(a.y - a.x)); }      // * W16^2
__device__ __forceinline__ cf cW3(cf a){ return make_float2(S1f*a.x + C1f*a.y, S1f*a.y - C1f*a.x); }  // * W16^3
__device__ __forceinline__ cf cW6(cf a){ return make_float2(R2f*(a.y - a.x), -R2f*(a.x + a.y)); }     // * W16^6
__device__ __forceinline__ cf cNW1(cf a){ return make_float2(-(C1f*a.x + S1f*a.y), S1f*a.x - C1f*a.y); } // * W16^9

// in-register 16-point DFT (natural in/out), radix-4 DIF
__device__ __forceinline__ void fft16(cf v[16]) {
    cf y[16];
    #pragma unroll
    for (int j1 = 0; j1 < 4; ++j1) {
        cf a0 = v[j1], a1 = v[j1+4], a2 = v[j1+8], a3 = v[j1+12];
        cf s0 = cadd(a0,a2), d0 = csub(a0,a2);
        cf s1 = cadd(a1,a3), d1 = csub(a1,a3);
        cf b0 = cadd(s0,s1);
        cf b1 = make_float2(d0.x + d1.y, d0.y - d1.x);
        cf b2 = csub(s0,s1);
        cf b3 = make_float2(d0.x - d1.y, d0.y + d1.x);
        if (j1 == 0)      { y[0]=b0; y[4]=b1;      y[8]=b2;          y[12]=b3; }
        else if (j1 == 1) { y[1]=b0; y[5]=cW1(b1); y[9]=cW2(b2);     y[13]=cW3(b3); }
        else if (j1 == 2) { y[2]=b0; y[6]=cW2(b1); y[10]=cmulNI(b2); y[14]=cW6(b3); }
        else              { y[3]=b0; y[7]=cW3(b1); y[11]=cW6(b2);    y[15]=cNW1(b3); }
    }
    #pragma unroll
    for (int p1 = 0; p1 < 4; ++p1) {
        cf c0 = y[4*p1], c1v = y[4*p1+1], c2v = y[4*p1+2], c3v = y[4*p1+3];
        cf s0 = cadd(c0,c2v), d0 = csub(c0,c2v);
        cf s1 = cadd(c1v,c3v), d1 = csub(c1v,c3v);
        v[p1]    = cadd(s0,s1);
        v[4+p1]  = make_float2(d0.x + d1.y, d0.y - d1.x);
        v[8+p1]  = csub(s0,s1);
        v[12+p1] = make_float2(d0.x - d1.y, d0.y + d1.x);
    }
}

// 64-lane sum via DPP; valid in lane 63
__device__ __forceinline__ float wred(float x) {
    x += __int_as_float(__builtin_amdgcn_update_dpp(0, __float_as_int(x), 0x111, 0xf, 0xf, false));
    x += __int_as_float(__builtin_amdgcn_update_dpp(0, __float_as_int(x), 0x112, 0xf, 0xf, false));
    x += __int_as_float(__builtin_amdgcn_update_dpp(0, __float_as_int(x), 0x114, 0xf, 0xf, false));
    x += __int_as_float(__builtin_amdgcn_update_dpp(0, __float_as_int(x), 0x118, 0xf, 0xf, false));
    x += __int_as_float(__builtin_amdgcn_update_dpp(0, __float_as_int(x), 0x142, 0xa, 0xf, false));
    x += __int_as_float(__builtin_amdgcn_update_dpp(0, __float_as_int(x), 0x143, 0xc, 0xf, false));
    return x;
}

__global__ __launch_bounds__(256, 4)
void fftmlp_r16sw(const float* __restrict__ x, const float* __restrict__ w1,
                  const float* __restrict__ w2, float* __restrict__ out) {
    __shared__ __align__(16) cf buf[4096];   // EXACTLY 32 KB -> 5 blocks/CU
    const int t = threadIdx.x;
    const int b = blockIdx.x;
    const cf* __restrict__ xr  = (const cf*)x + (size_t)b * 4096;
    const cf* __restrict__ w1c = (const cf*)w1;
    const cf* __restrict__ w2c = (const cf*)w2;
    float sn, cs;

    // ---- pass A: global x*w1 -> fft16 over stride-256 -> twiddle -> LDS ----
    {
        cf v[16];
        #pragma unroll
        for (int q = 0; q < 16; ++q)
            v[q] = cmul(xr[t + 256*q], w1c[t + 256*q]);
        fft16(v);
        __sincosf(-TWO_PI * (float)t * (1.0f/4096.0f), &sn, &cs);
        cf w = make_float2(cs, sn);
        buf[SIDX(t)] = v[0];
        cf tw = w;
        #pragma unroll
        for (int p = 1; p < 16; ++p) {
            buf[SIDX(p*256 + t)] = cmul(v[p], tw);
            tw = cmul(tw, w);
        }
    }
    __syncthreads();

    // ---- pass B: within 256-blocks, stride 16, twiddle W_256^jp, in place ----
    {
        const int p    = t >> 4;
        const int jp   = t & 15;
        const int base = p*256 + jp;
        cf u[16];
        #pragma unroll
        for (int q = 0; q < 16; ++q) u[q] = buf[SIDX(base + 16*q)];
        fft16(u);
        __sincosf(-TWO_PI * (float)jp * (1.0f/256.0f), &sn, &cs);
        cf w = make_float2(cs, sn);
        buf[SIDX(base)] = u[0];
        cf tw = w;
        #pragma unroll
        for (int pp = 1; pp < 16; ++pp) {
            buf[SIDX(base + 16*pp)] = cmul(u[pp], tw);
            tw = cmul(tw, w);
        }
    }
    __syncthreads();

    // ---- final: read contiguous 16 (b128), then fold layer 2 ----
    cf z[16];
    #pragma unroll
    for (int j2 = 0; j2 < 8; ++j2) {
        float4 q = *reinterpret_cast<const float4*>(&buf[SIDX(16*t + 2*j2)]);
        z[2*j2]   = make_float2(q.x, q.y);
        z[2*j2+1] = make_float2(q.z, q.w);
    }
    __syncthreads();   // all buf reads done -> safe to alias sred onto buf

    float rv[10];
    {
        cf A[4][4];
        #pragma unroll
        for (int bb = 0; bb < 4; ++bb) {
            cf a0 = z[bb], a1 = z[bb+4], a2 = z[bb+8], a3 = z[bb+12];
            cf s0 = cadd(a0,a2), d0 = csub(a0,a2);
            cf s1 = cadd(a1,a3), d1 = csub(a1,a3);
            A[bb][0] = cadd(s0,s1);
            A[bb][1] = make_float2(d0.x + d1.y, d0.y - d1.x);
            A[bb][2] = csub(s0,s1);
            A[bb][3] = make_float2(d0.x - d1.y, d0.y + d1.x);
        }
        cf F0 = cadd(cadd(A[0][0], A[1][0]),      cadd(A[2][0],      A[3][0]));
        cf F1 = cadd(cadd(A[0][1], cW1(A[1][1])), cadd(cW2(A[2][1]), cW3(A[3][1])));
        cf F2 = cadd(cadd(A[0][2], cW2(A[1][2])), cadd(cmulNI(A[2][2]), cW6(A[3][2])));
        cf F3 = cadd(cadd(A[0][3], cW3(A[1][3])), cadd(cW6(A[2][3]), cNW1(A[3][3])));

        // bin n = 256*p'' + c0, c0 = 16*(t&15) + (t>>4)
        const int c0i = ((t & 15) << 4) | (t >> 4);
        cf h, P0, P1, P2, P3;
        h = make_float2(fmaxf(F0.x,0.f), fmaxf(F0.y,0.f)); P0 = cmul(h, w2c[c0i]);
        h = make_float2(fmaxf(F1.x,0.f), fmaxf(F1.y,0.f)); P1 = cmul(h, w2c[256 + c0i]);
        h = make_float2(fmaxf(F2.x,0.f), fmaxf(F2.y,0.f)); P2 = cmul(h, w2c[512 + c0i]);
        h = make_float2(fmaxf(F3.x,0.f), fmaxf(F3.y,0.f)); P3 = cmul(h, w2c[768 + c0i]);

        cf s0 = cadd(P0,P2), d0 = csub(P0,P2);
        cf s1 = cadd(P1,P3), d1 = csub(P1,P3);
        cf G0 = cadd(s0,s1);
        cf G1 = make_float2(d0.x + d1.y, d0.y - d1.x);
        cf G2 = csub(s0,s1);
        cf G3 = make_float2(d0.x - d1.y, d0.y + d1.x);
        __sincosf(-TWO_PI * (float)c0i * (1.0f/1024.0f), &sn, &cs);
        cf wk = make_float2(cs, sn);
        cf r = wk;
        cf a1 = cmul(G1, r); r = cmul(r, wk);
        cf a2 = cmul(G2, r); r = cmul(r, wk);
        cf a3 = cmul(G3, r); r = cmul(r, wk);
        cf a4 = cmul(G0, r);                  // k=4: (-i)^{4p''}=1 -> G0
        rv[0]=G0.x; rv[1]=G0.y; rv[2]=a1.x; rv[3]=a1.y; rv[4]=a2.x;
        rv[5]=a2.y; rv[6]=a3.x; rv[7]=a3.y; rv[8]=a4.x; rv[9]=a4.y;
    }

    // ---- reduce 256 threads -> 10 floats (sred aliased onto buf) ----
    float* sred = (float*)buf;
    #pragma unroll
    for (int i = 0; i < 10; ++i) rv[i] = wred(rv[i]);
    const int lane = t & 63, wv = t >> 6;
    if (lane == 63) {
        #pragma unroll
        for (int i = 0; i < 10; ++i) sred[wv*10 + i] = rv[i];
    }
    __syncthreads();
    if (t < 10) {
        out[b*10 + t] = sred[t] + sred[10+t] + sred[20+t] + sred[30+t];
    }
}

extern "C" void kernel_launch(void* const* d_in, const int* in_sizes, int n_in,
                              void* d_out, int out_size, void* d_ws, size_t ws_size,
                              hipStream_t stream) {
    const float* x  = (const float*)d_in[0];
    const float* w1 = (const float*)d_in[1];
    const float* w2 = (const float*)d_in[2];
    float* out = (float*)d_out;
    fftmlp_r16sw<<<NBLK, 256, 0, stream>>>(x, w1, w2, out);
}

// Round 11
// 78.362 us; speedup vs baseline: 6.2490x; 1.0077x over previous
//
#include <hip/hip_runtime.h>

#define NBLK 8192
#define C1f 0.92387953251128674f
#define S1f 0.38268343236508978f
#define R2f 0.70710678118654752f
#define TWO_PI 6.28318530717958648f

// bank swizzle: XOR cf-index bits [3:1] with bits [6:4]. Involution on 0..4095.
#define SIDX(c) ((c) ^ ((((c) >> 4) & 7) << 1))

typedef float2 cf;

__device__ __forceinline__ cf cadd(cf a, cf b){ return make_float2(a.x+b.x, a.y+b.y); }
__device__ __forceinline__ cf csub(cf a, cf b){ return make_float2(a.x-b.x, a.y-b.y); }
__device__ __forceinline__ cf cmul(cf a, cf b){ return make_float2(a.x*b.x - a.y*b.y, a.x*b.y + a.y*b.x); }
__device__ __forceinline__ cf cmulNI(cf a){ return make_float2(a.y, -a.x); }              // * (-i)
__device__ __forceinline__ cf cW1(cf a){ return make_float2(C1f*a.x + S1f*a.y, C1f*a.y - S1f*a.x); }  // * W16^1
__device__ __forceinline__ cf cW2(cf a){ return make_float2(R2f*(a.x + a.y), R2f*(a.y - a.x)); }      // * W16^2
__device__ __forceinline__ cf cW3(cf a){ return make_float2(S1f*a.x + C1f*a.y, S1f*a.y - C1f*a.x); }  // * W16^3
__device__ __forceinline__ cf cW6(cf a){ return make_float2(R2f*(a.y - a.x), -R2f*(a.x + a.y)); }     // * W16^6
__device__ __forceinline__ cf cNW1(cf a){ return make_float2(-(C1f*a.x + S1f*a.y), S1f*a.x - C1f*a.y); } // * W16^9

// in-register 16-point DFT (natural in/out), radix-4 DIF
__device__ __forceinline__ void fft16(cf v[16]) {
    cf y[16];
    #pragma unroll
    for (int j1 = 0; j1 < 4; ++j1) {
        cf a0 = v[j1], a1 = v[j1+4], a2 = v[j1+8], a3 = v[j1+12];
        cf s0 = cadd(a0,a2), d0 = csub(a0,a2);
        cf s1 = cadd(a1,a3), d1 = csub(a1,a3);
        cf b0 = cadd(s0,s1);
        cf b1 = make_float2(d0.x + d1.y, d0.y - d1.x);
        cf b2 = csub(s0,s1);
        cf b3 = make_float2(d0.x - d1.y, d0.y + d1.x);
        if (j1 == 0)      { y[0]=b0; y[4]=b1;      y[8]=b2;          y[12]=b3; }
        else if (j1 == 1) { y[1]=b0; y[5]=cW1(b1); y[9]=cW2(b2);     y[13]=cW3(b3); }
        else if (j1 == 2) { y[2]=b0; y[6]=cW2(b1); y[10]=cmulNI(b2); y[14]=cW6(b3); }
        else              { y[3]=b0; y[7]=cW3(b1); y[11]=cW6(b2);    y[15]=cNW1(b3); }
    }
    #pragma unroll
    for (int p1 = 0; p1 < 4; ++p1) {
        cf c0 = y[4*p1], c1v = y[4*p1+1], c2v = y[4*p1+2], c3v = y[4*p1+3];
        cf s0 = cadd(c0,c2v), d0 = csub(c0,c2v);
        cf s1 = cadd(c1v,c3v), d1 = csub(c1v,c3v);
        v[p1]    = cadd(s0,s1);
        v[4+p1]  = make_float2(d0.x + d1.y, d0.y - d1.x);
        v[8+p1]  = csub(s0,s1);
        v[12+p1] = make_float2(d0.x - d1.y, d0.y + d1.x);
    }
}

// 64-lane sum via DPP; valid in lane 63
__device__ __forceinline__ float wred(float x) {
    x += __int_as_float(__builtin_amdgcn_update_dpp(0, __float_as_int(x), 0x111, 0xf, 0xf, false));
    x += __int_as_float(__builtin_amdgcn_update_dpp(0, __float_as_int(x), 0x112, 0xf, 0xf, false));
    x += __int_as_float(__builtin_amdgcn_update_dpp(0, __float_as_int(x), 0x114, 0xf, 0xf, false));
    x += __int_as_float(__builtin_amdgcn_update_dpp(0, __float_as_int(x), 0x118, 0xf, 0xf, false));
    x += __int_as_float(__builtin_amdgcn_update_dpp(0, __float_as_int(x), 0x142, 0xa, 0xf, false));
    x += __int_as_float(__builtin_amdgcn_update_dpp(0, __float_as_int(x), 0x143, 0xc, 0xf, false));
    return x;
}

__global__ __launch_bounds__(256, 4)
void fftmlp_r16st(const float* __restrict__ x, const float* __restrict__ w1,
                  const float* __restrict__ w2, float* __restrict__ out) {
    __shared__ __align__(16) cf buf[4096];   // exactly 32 KB
    const int t = threadIdx.x;
    const int b = blockIdx.x;

    // ---- phase stagger: initial cohort only. Co-resident blocks on a CU are
    // ~256 apart in blockIdx (round-robin over 8 XCD x 32 CU); give each of
    // the 4 initial residents a ~2.4 us offset so load phases interleave.
    if (b < 1024) {
        const int cls = b >> 8;              // 0..3
        for (int i = 0; i < cls; ++i)
            __builtin_amdgcn_s_sleep(90);    // 90*64 clk ~= 2.4 us
    }

    const cf* __restrict__ xr  = (const cf*)x + (size_t)b * 4096;
    const cf* __restrict__ w1c = (const cf*)w1;
    const cf* __restrict__ w2c = (const cf*)w2;
    float sn, cs;

    // ---- pass A: global x*w1 -> fft16 over stride-256 -> twiddle -> LDS ----
    {
        cf v[16];
        #pragma unroll
        for (int q = 0; q < 16; ++q)
            v[q] = cmul(xr[t + 256*q], w1c[t + 256*q]);
        fft16(v);
        __sincosf(-TWO_PI * (float)t * (1.0f/4096.0f), &sn, &cs);
        cf w = make_float2(cs, sn);
        buf[SIDX(t)] = v[0];
        cf tw = w;
        #pragma unroll
        for (int p = 1; p < 16; ++p) {
            buf[SIDX(p*256 + t)] = cmul(v[p], tw);
            tw = cmul(tw, w);
        }
    }
    __syncthreads();

    // ---- pass B: within 256-blocks, stride 16, twiddle W_256^jp, in place ----
    {
        const int p    = t >> 4;
        const int jp   = t & 15;
        const int base = p*256 + jp;
        cf u[16];
        #pragma unroll
        for (int q = 0; q < 16; ++q) u[q] = buf[SIDX(base + 16*q)];
        fft16(u);
        __sincosf(-TWO_PI * (float)jp * (1.0f/256.0f), &sn, &cs);
        cf w = make_float2(cs, sn);
        buf[SIDX(base)] = u[0];
        cf tw = w;
        #pragma unroll
        for (int pp = 1; pp < 16; ++pp) {
            buf[SIDX(base + 16*pp)] = cmul(u[pp], tw);
            tw = cmul(tw, w);
        }
    }
    __syncthreads();

    // ---- final: read contiguous 16 (b128), then fold layer 2 ----
    cf z[16];
    #pragma unroll
    for (int j2 = 0; j2 < 8; ++j2) {
        float4 q = *reinterpret_cast<const float4*>(&buf[SIDX(16*t + 2*j2)]);
        z[2*j2]   = make_float2(q.x, q.y);
        z[2*j2+1] = make_float2(q.z, q.w);
    }
    __syncthreads();   // all buf reads done -> safe to alias sred onto buf

    float rv[10];
    {
        cf A[4][4];
        #pragma unroll
        for (int bb = 0; bb < 4; ++bb) {
            cf a0 = z[bb], a1 = z[bb+4], a2 = z[bb+8], a3 = z[bb+12];
            cf s0 = cadd(a0,a2), d0 = csub(a0,a2);
            cf s1 = cadd(a1,a3), d1 = csub(a1,a3);
            A[bb][0] = cadd(s0,s1);
            A[bb][1] = make_float2(d0.x + d1.y, d0.y - d1.x);
            A[bb][2] = csub(s0,s1);
            A[bb][3] = make_float2(d0.x - d1.y, d0.y + d1.x);
        }
        cf F0 = cadd(cadd(A[0][0], A[1][0]),      cadd(A[2][0],      A[3][0]));
        cf F1 = cadd(cadd(A[0][1], cW1(A[1][1])), cadd(cW2(A[2][1]), cW3(A[3][1])));
        cf F2 = cadd(cadd(A[0][2], cW2(A[1][2])), cadd(cmulNI(A[2][2]), cW6(A[3][2])));
        cf F3 = cadd(cadd(A[0][3], cW3(A[1][3])), cadd(cW6(A[2][3]), cNW1(A[3][3])));

        // bin n = 256*p'' + c0, c0 = 16*(t&15) + (t>>4)
        const int c0i = ((t & 15) << 4) | (t >> 4);
        cf h, P0, P1, P2, P3;
        h = make_float2(fmaxf(F0.x,0.f), fmaxf(F0.y,0.f)); P0 = cmul(h, w2c[c0i]);
        h = make_float2(fmaxf(F1.x,0.f), fmaxf(F1.y,0.f)); P1 = cmul(h, w2c[256 + c0i]);
        h = make_float2(fmaxf(F2.x,0.f), fmaxf(F2.y,0.f)); P2 = cmul(h, w2c[512 + c0i]);
        h = make_float2(fmaxf(F3.x,0.f), fmaxf(F3.y,0.f)); P3 = cmul(h, w2c[768 + c0i]);

        cf s0 = cadd(P0,P2), d0 = csub(P0,P2);
        cf s1 = cadd(P1,P3), d1 = csub(P1,P3);
        cf G0 = cadd(s0,s1);
        cf G1 = make_float2(d0.x + d1.y, d0.y - d1.x);
        cf G2 = csub(s0,s1);
        cf G3 = make_float2(d0.x - d1.y, d0.y + d1.x);
        __sincosf(-TWO_PI * (float)c0i * (1.0f/1024.0f), &sn, &cs);
        cf wk = make_float2(cs, sn);
        cf r = wk;
        cf a1 = cmul(G1, r); r = cmul(r, wk);
        cf a2 = cmul(G2, r); r = cmul(r, wk);
        cf a3 = cmul(G3, r); r = cmul(r, wk);
        cf a4 = cmul(G0, r);                  // k=4: (-i)^{4p''}=1 -> G0
        rv[0]=G0.x; rv[1]=G0.y; rv[2]=a1.x; rv[3]=a1.y; rv[4]=a2.x;
        rv[5]=a2.y; rv[6]=a3.x; rv[7]=a3.y; rv[8]=a4.x; rv[9]=a4.y;
    }

    // ---- reduce 256 threads -> 10 floats (sred aliased onto buf) ----
    float* sred = (float*)buf;
    #pragma unroll
    for (int i = 0; i < 10; ++i) rv[i] = wred(rv[i]);
    const int lane = t & 63, wv = t >> 6;
    if (lane == 63) {
        #pragma unroll
        for (int i = 0; i < 10; ++i) sred[wv*10 + i] = rv[i];
    }
    __syncthreads();
    if (t < 10) {
        out[b*10 + t] = sred[t] + sred[10+t] + sred[20+t] + sred[30+t];
    }
}

extern "C" void kernel_launch(void* const* d_in, const int* in_sizes, int n_in,
                              void* d_out, int out_size, void* d_ws, size_t ws_size,
                              hipStream_t stream) {
    const float* x  = (const float*)d_in[0];
    const float* w1 = (const float*)d_in[1];
    const float* w2 = (const float*)d_in[2];
    float* out = (float*)d_out;
    fftmlp_r16st<<<NBLK, 256, 0, stream>>>(x, w1, w2, out);
}

// Round 13
// 63.077 us; speedup vs baseline: 7.7633x; 1.2423x over previous
//
#include <hip/hip_runtime.h>

#define NBLK 8192
#define C1f 0.92387953251128674f
#define S1f 0.38268343236508978f
#define R2f 0.70710678118654752f
#define TWO_PI 6.28318530717958648f

// bank swizzle: XOR cf-index bits [3:1] with bits [6:4]. Involution on 0..4095.
#define SIDX(c) ((c) ^ ((((c) >> 4) & 7) << 1))

typedef float cf __attribute__((ext_vector_type(2)));
typedef float f4 __attribute__((ext_vector_type(4)));

__device__ __forceinline__ cf mkcf(float a, float b){ cf r; r.x = a; r.y = b; return r; }

// ---------- VOP3P packed-f32 helpers: 2 f32 lanes per instruction ----------
__device__ __forceinline__ cf pk_add(cf a, cf b){
    cf r; asm("v_pk_add_f32 %0, %1, %2" : "=v"(r) : "v"(a), "v"(b)); return r;
}
__device__ __forceinline__ cf pk_sub(cf a, cf b){
    cf r; asm("v_pk_add_f32 %0, %1, %2 neg_lo:[0,1] neg_hi:[0,1]" : "=v"(r) : "v"(a), "v"(b)); return r;
}
// a - i*b = (a.x + b.y, a.y - b.x)
__device__ __forceinline__ cf pk_mi(cf a, cf b){
    cf r; asm("v_pk_add_f32 %0, %1, %2 op_sel:[0,1] op_sel_hi:[1,0] neg_hi:[0,1]" : "=v"(r) : "v"(a), "v"(b)); return r;
}
// a + i*b = (a.x - b.y, a.y + b.x)
__device__ __forceinline__ cf pk_pi(cf a, cf b){
    cf r; asm("v_pk_add_f32 %0, %1, %2 op_sel:[0,1] op_sel_hi:[1,0] neg_lo:[0,1]" : "=v"(r) : "v"(a), "v"(b)); return r;
}
// (-i)*a = (a.y, -a.x)
__device__ __forceinline__ cf pk_ni(cf a){
    cf r; asm("v_pk_add_f32 %0, %1, 0 op_sel:[1,0] op_sel_hi:[0,0] neg_hi:[1,0]" : "=v"(r) : "v"(a)); return r;
}
// ReLU both halves: no v_pk_max_f32 on gfx950 (R12 lesson) -> 2 scalar max
__device__ __forceinline__ cf relu2(cf a){
    return mkcf(fmaxf(a.x, 0.0f), fmaxf(a.y, 0.0f));
}
// full complex multiply a*b in 2 instructions
__device__ __forceinline__ cf pk_cmul(cf a, cf b){
    cf t, r;
    asm("v_pk_mul_f32 %0, %1, %2 op_sel:[0,0] op_sel_hi:[0,1]"
        : "=v"(t) : "v"(a), "v"(b));                       // (a.x*b.x, a.x*b.y)
    asm("v_pk_fma_f32 %0, %1, %2, %3 op_sel:[1,1,0] op_sel_hi:[1,0,1] neg_lo:[1,0,0] neg_hi:[0,0,0]"
        : "=v"(r) : "v"(a), "v"(b), "v"(t));               // (-a.y*b.y+., a.y*b.x+.)
    return r;
}

// in-register 16-point DFT (natural in/out), radix-4 DIF, packed ops
__device__ __forceinline__ void fft16pk(cf v[16]) {
    const cf K1 = mkcf(C1f,-S1f), K2 = mkcf(R2f,-R2f), K3 = mkcf(S1f,-C1f),
             K6 = mkcf(-R2f,-R2f), K9 = mkcf(-C1f,S1f);
    cf y[16];
    #pragma unroll
    for (int j1 = 0; j1 < 4; ++j1) {
        cf a0 = v[j1], a1 = v[j1+4], a2 = v[j1+8], a3 = v[j1+12];
        cf s0 = pk_add(a0,a2), d0 = pk_sub(a0,a2);
        cf s1 = pk_add(a1,a3), d1 = pk_sub(a1,a3);
        cf b0 = pk_add(s0,s1);
        cf b1 = pk_mi(d0,d1);
        cf b2 = pk_sub(s0,s1);
        cf b3 = pk_pi(d0,d1);
        if (j1 == 0)      { y[0]=b0; y[4]=b1;             y[8]=b2;             y[12]=b3; }
        else if (j1 == 1) { y[1]=b0; y[5]=pk_cmul(b1,K1); y[9]=pk_cmul(b2,K2); y[13]=pk_cmul(b3,K3); }
        else if (j1 == 2) { y[2]=b0; y[6]=pk_cmul(b1,K2); y[10]=pk_ni(b2);     y[14]=pk_cmul(b3,K6); }
        else              { y[3]=b0; y[7]=pk_cmul(b1,K3); y[11]=pk_cmul(b2,K6);y[15]=pk_cmul(b3,K9); }
    }
    #pragma unroll
    for (int p1 = 0; p1 < 4; ++p1) {
        cf c0 = y[4*p1], c1v = y[4*p1+1], c2v = y[4*p1+2], c3v = y[4*p1+3];
        cf s0 = pk_add(c0,c2v), d0 = pk_sub(c0,c2v);
        cf s1 = pk_add(c1v,c3v), d1 = pk_sub(c1v,c3v);
        v[p1]    = pk_add(s0,s1);
        v[4+p1]  = pk_mi(d0,d1);
        v[8+p1]  = pk_sub(s0,s1);
        v[12+p1] = pk_pi(d0,d1);
    }
}

// 64-lane sum via DPP; valid in lane 63
__device__ __forceinline__ float wred(float x) {
    x += __int_as_float(__builtin_amdgcn_update_dpp(0, __float_as_int(x), 0x111, 0xf, 0xf, false));
    x += __int_as_float(__builtin_amdgcn_update_dpp(0, __float_as_int(x), 0x112, 0xf, 0xf, false));
    x += __int_as_float(__builtin_amdgcn_update_dpp(0, __float_as_int(x), 0x114, 0xf, 0xf, false));
    x += __int_as_float(__builtin_amdgcn_update_dpp(0, __float_as_int(x), 0x118, 0xf, 0xf, false));
    x += __int_as_float(__builtin_amdgcn_update_dpp(0, __float_as_int(x), 0x142, 0xa, 0xf, false));
    x += __int_as_float(__builtin_amdgcn_update_dpp(0, __float_as_int(x), 0x143, 0xc, 0xf, false));
    return x;
}

__global__ __launch_bounds__(256, 4)
void fftmlp_pk(const float* __restrict__ x, const float* __restrict__ w1,
               const float* __restrict__ w2, float* __restrict__ out) {
    __shared__ __align__(16) cf buf[4096];   // exactly 32 KB
    const int t = threadIdx.x;
    const int b = blockIdx.x;
    const cf* __restrict__ xr  = (const cf*)x + (size_t)b * 4096;
    const cf* __restrict__ w1c = (const cf*)w1;
    const cf* __restrict__ w2c = (const cf*)w2;
    float sn, cs;

    // ---- pass A: global x*w1 -> fft16 over stride-256 -> twiddle -> LDS ----
    {
        cf v[16];
        #pragma unroll
        for (int q = 0; q < 16; ++q)
            v[q] = pk_cmul(xr[t + 256*q], w1c[t + 256*q]);
        fft16pk(v);
        __sincosf(-TWO_PI * (float)t * (1.0f/4096.0f), &sn, &cs);
        cf w = mkcf(cs, sn);
        buf[SIDX(t)] = v[0];
        cf tw = w;
        #pragma unroll
        for (int p = 1; p < 16; ++p) {
            buf[SIDX(p*256 + t)] = pk_cmul(v[p], tw);
            tw = pk_cmul(tw, w);
        }
    }
    __syncthreads();

    // ---- pass B: within 256-blocks, stride 16, twiddle W_256^jp, in place ----
    {
        const int p    = t >> 4;
        const int jp   = t & 15;
        const int base = p*256 + jp;
        cf u[16];
        #pragma unroll
        for (int q = 0; q < 16; ++q) u[q] = buf[SIDX(base + 16*q)];
        fft16pk(u);
        __sincosf(-TWO_PI * (float)jp * (1.0f/256.0f), &sn, &cs);
        cf w = mkcf(cs, sn);
        buf[SIDX(base)] = u[0];
        cf tw = w;
        #pragma unroll
        for (int pp = 1; pp < 16; ++pp) {
            buf[SIDX(base + 16*pp)] = pk_cmul(u[pp], tw);
            tw = pk_cmul(tw, w);
        }
    }
    __syncthreads();

    // ---- final: read contiguous 16 (b128), fold layer 2 ----
    cf z[16];
    #pragma unroll
    for (int j2 = 0; j2 < 8; ++j2) {
        f4 q = *reinterpret_cast<const f4*>(&buf[SIDX(16*t + 2*j2)]);
        z[2*j2]   = mkcf(q.x, q.y);
        z[2*j2+1] = mkcf(q.z, q.w);
    }
    __syncthreads();   // all buf reads done -> safe to alias sred onto buf

    float rv[10];
    {
        const cf K1 = mkcf(C1f,-S1f), K2 = mkcf(R2f,-R2f), K3 = mkcf(S1f,-C1f),
                 K6 = mkcf(-R2f,-R2f), K9 = mkcf(-C1f,S1f);
        cf A[4][4];
        #pragma unroll
        for (int bb = 0; bb < 4; ++bb) {
            cf a0 = z[bb], a1 = z[bb+4], a2 = z[bb+8], a3 = z[bb+12];
            cf s0 = pk_add(a0,a2), d0 = pk_sub(a0,a2);
            cf s1 = pk_add(a1,a3), d1 = pk_sub(a1,a3);
            A[bb][0] = pk_add(s0,s1);
            A[bb][1] = pk_mi(d0,d1);
            A[bb][2] = pk_sub(s0,s1);
            A[bb][3] = pk_pi(d0,d1);
        }
        cf F0 = pk_add(pk_add(A[0][0], A[1][0]),
                       pk_add(A[2][0], A[3][0]));
        cf F1 = pk_add(pk_add(A[0][1], pk_cmul(A[1][1],K1)),
                       pk_add(pk_cmul(A[2][1],K2), pk_cmul(A[3][1],K3)));
        cf F2 = pk_add(pk_add(A[0][2], pk_cmul(A[1][2],K2)),
                       pk_add(pk_ni(A[2][2]), pk_cmul(A[3][2],K6)));
        cf F3 = pk_add(pk_add(A[0][3], pk_cmul(A[1][3],K3)),
                       pk_add(pk_cmul(A[2][3],K6), pk_cmul(A[3][3],K9)));

        // bin n = 256*p'' + c0, c0 = 16*(t&15) + (t>>4)
        const int c0i = ((t & 15) << 4) | (t >> 4);
        cf Q0 = pk_cmul(relu2(F0), w2c[c0i]);
        cf Q1 = pk_cmul(relu2(F1), w2c[256 + c0i]);
        cf Q2 = pk_cmul(relu2(F2), w2c[512 + c0i]);
        cf Q3 = pk_cmul(relu2(F3), w2c[768 + c0i]);

        cf s0 = pk_add(Q0,Q2), d0 = pk_sub(Q0,Q2);
        cf s1 = pk_add(Q1,Q3), d1 = pk_sub(Q1,Q3);
        cf G0 = pk_add(s0,s1);
        cf G1 = pk_mi(d0,d1);
        cf G2 = pk_sub(s0,s1);
        cf G3 = pk_pi(d0,d1);
        __sincosf(-TWO_PI * (float)c0i * (1.0f/1024.0f), &sn, &cs);
        cf wk = mkcf(cs, sn);
        cf r1 = wk;
        cf a1 = pk_cmul(G1, r1);
        cf r2 = pk_cmul(r1, wk);
        cf a2 = pk_cmul(G2, r2);
        cf r3 = pk_cmul(r2, wk);
        cf a3 = pk_cmul(G3, r3);
        cf r4 = pk_cmul(r3, wk);
        cf a4 = pk_cmul(G0, r4);              // k=4: (-i)^{4p''}=1 -> G0
        rv[0]=G0.x; rv[1]=G0.y; rv[2]=a1.x; rv[3]=a1.y; rv[4]=a2.x;
        rv[5]=a2.y; rv[6]=a3.x; rv[7]=a3.y; rv[8]=a4.x; rv[9]=a4.y;
    }

    // ---- reduce 256 threads -> 10 floats (sred aliased onto buf) ----
    float* sred = (float*)buf;
    #pragma unroll
    for (int i = 0; i < 10; ++i) rv[i] = wred(rv[i]);
    const int lane = t & 63, wv = t >> 6;
    if (lane == 63) {
        #pragma unroll
        for (int i = 0; i < 10; ++i) sred[wv*10 + i] = rv[i];
    }
    __syncthreads();
    if (t < 10) {
        out[b*10 + t] = sred[t] + sred[10+t] + sred[20+t] + sred[30+t];
    }
}

extern "C" void kernel_launch(void* const* d_in, const int* in_sizes, int n_in,
                              void* d_out, int out_size, void* d_ws, size_t ws_size,
                              hipStream_t stream) {
    const float* x  = (const float*)d_in[0];
    const float* w1 = (const float*)d_in[1];
    const float* w2 = (const float*)d_in[2];
    float* out = (float*)d_out;
    fftmlp_pk<<<NBLK, 256, 0, stream>>>(x, w1, w2, out);
}

// Round 15
// 62.250 us; speedup vs baseline: 7.8663x; 1.0133x over previous
//
#include <hip/hip_runtime.h>

#define NBLK 8192
#define C1f 0.92387953251128674f
#define S1f 0.38268343236508978f
#define R2f 0.70710678118654752f
#define TWO_PI 6.28318530717958648f

// bank swizzle: XOR cf-index bits [3:1] with bits [6:4]. Involution on 0..4095.
#define SIDX(c) ((c) ^ ((((c) >> 4) & 7) << 1))

typedef float cf __attribute__((ext_vector_type(2)));
typedef float f4 __attribute__((ext_vector_type(4)));

__device__ __forceinline__ cf mkcf(float a, float b){ cf r; r.x = a; r.y = b; return r; }

// ---------- VOP3P packed-f32 helpers ----------
__device__ __forceinline__ cf pk_add(cf a, cf b){
    cf r; asm("v_pk_add_f32 %0, %1, %2" : "=v"(r) : "v"(a), "v"(b)); return r;
}
__device__ __forceinline__ cf pk_sub(cf a, cf b){
    cf r; asm("v_pk_add_f32 %0, %1, %2 neg_lo:[0,1] neg_hi:[0,1]" : "=v"(r) : "v"(a), "v"(b)); return r;
}
// a - i*b = (a.x + b.y, a.y - b.x)
__device__ __forceinline__ cf pk_mi(cf a, cf b){
    cf r; asm("v_pk_add_f32 %0, %1, %2 op_sel:[0,1] op_sel_hi:[1,0] neg_hi:[0,1]" : "=v"(r) : "v"(a), "v"(b)); return r;
}
// a + i*b = (a.x - b.y, a.y + b.x)
__device__ __forceinline__ cf pk_pi(cf a, cf b){
    cf r; asm("v_pk_add_f32 %0, %1, %2 op_sel:[0,1] op_sel_hi:[1,0] neg_lo:[0,1]" : "=v"(r) : "v"(a), "v"(b)); return r;
}
// (-i)*a = (a.y, -a.x)
__device__ __forceinline__ cf pk_ni(cf a){
    cf r; asm("v_pk_add_f32 %0, %1, 0 op_sel:[1,0] op_sel_hi:[0,0] neg_hi:[1,0]" : "=v"(r) : "v"(a)); return r;
}
// ReLU both halves (no v_pk_max_f32 on gfx950)
__device__ __forceinline__ cf relu2(cf a){
    return mkcf(fmaxf(a.x, 0.0f), fmaxf(a.y, 0.0f));
}
// complex multiply a*b, both runtime (VGPR)
__device__ __forceinline__ cf pk_cmul(cf a, cf b){
    cf t, r;
    asm("v_pk_mul_f32 %0, %1, %2 op_sel:[0,0] op_sel_hi:[0,1]"
        : "=v"(t) : "v"(a), "v"(b));
    asm("v_pk_fma_f32 %0, %1, %2, %3 op_sel:[1,1,0] op_sel_hi:[1,0,1] neg_lo:[1,0,0] neg_hi:[0,0,0]"
        : "=v"(r) : "v"(a), "v"(b), "v"(t));
    return r;
}
// complex multiply a*K, K compile-time -> SGPR pair (saves VGPRs; 1 SGPR src legal in VOP3P)
__device__ __forceinline__ cf pk_cmuls(cf a, cf b){
    cf t, r;
    asm("v_pk_mul_f32 %0, %1, %2 op_sel:[0,0] op_sel_hi:[0,1]"
        : "=v"(t) : "v"(a), "s"(b));
    asm("v_pk_fma_f32 %0, %1, %2, %3 op_sel:[1,1,0] op_sel_hi:[1,0,1] neg_lo:[1,0,0] neg_hi:[0,0,0]"
        : "=v"(r) : "v"(a), "s"(b), "v"(t));
    return r;
}

// in-register 16-point DFT (natural in/out), radix-4 DIF, packed ops, SGPR constants
__device__ __forceinline__ void fft16pk(cf v[16]) {
    const cf K1 = mkcf(C1f,-S1f), K2 = mkcf(R2f,-R2f), K3 = mkcf(S1f,-C1f),
             K6 = mkcf(-R2f,-R2f), K9 = mkcf(-C1f,S1f);
    cf y[16];
    #pragma unroll
    for (int j1 = 0; j1 < 4; ++j1) {
        cf a0 = v[j1], a1 = v[j1+4], a2 = v[j1+8], a3 = v[j1+12];
        cf s0 = pk_add(a0,a2), d0 = pk_sub(a0,a2);
        cf s1 = pk_add(a1,a3), d1 = pk_sub(a1,a3);
        cf b0 = pk_add(s0,s1);
        cf b1 = pk_mi(d0,d1);
        cf b2 = pk_sub(s0,s1);
        cf b3 = pk_pi(d0,d1);
        if (j1 == 0)      { y[0]=b0; y[4]=b1;              y[8]=b2;              y[12]=b3; }
        else if (j1 == 1) { y[1]=b0; y[5]=pk_cmuls(b1,K1); y[9]=pk_cmuls(b2,K2); y[13]=pk_cmuls(b3,K3); }
        else if (j1 == 2) { y[2]=b0; y[6]=pk_cmuls(b1,K2); y[10]=pk_ni(b2);      y[14]=pk_cmuls(b3,K6); }
        else              { y[3]=b0; y[7]=pk_cmuls(b1,K3); y[11]=pk_cmuls(b2,K6);y[15]=pk_cmuls(b3,K9); }
    }
    #pragma unroll
    for (int p1 = 0; p1 < 4; ++p1) {
        cf c0 = y[4*p1], c1v = y[4*p1+1], c2v = y[4*p1+2], c3v = y[4*p1+3];
        cf s0 = pk_add(c0,c2v), d0 = pk_sub(c0,c2v);
        cf s1 = pk_add(c1v,c3v), d1 = pk_sub(c1v,c3v);
        v[p1]    = pk_add(s0,s1);
        v[4+p1]  = pk_mi(d0,d1);
        v[8+p1]  = pk_sub(s0,s1);
        v[12+p1] = pk_pi(d0,d1);
    }
}

// 64-lane sum via DPP; valid in lane 63
__device__ __forceinline__ float wred(float x) {
    x += __int_as_float(__builtin_amdgcn_update_dpp(0, __float_as_int(x), 0x111, 0xf, 0xf, false));
    x += __int_as_float(__builtin_amdgcn_update_dpp(0, __float_as_int(x), 0x112, 0xf, 0xf, false));
    x += __int_as_float(__builtin_amdgcn_update_dpp(0, __float_as_int(x), 0x114, 0xf, 0xf, false));
    x += __int_as_float(__builtin_amdgcn_update_dpp(0, __float_as_int(x), 0x118, 0xf, 0xf, false));
    x += __int_as_float(__builtin_amdgcn_update_dpp(0, __float_as_int(x), 0x142, 0xa, 0xf, false));
    x += __int_as_float(__builtin_amdgcn_update_dpp(0, __float_as_int(x), 0x143, 0xc, 0xf, false));
    return x;
}

__global__ __launch_bounds__(256, 4)
void fftmlp_pkd(const float* __restrict__ x, const float* __restrict__ w1,
                const float* __restrict__ w2, float* __restrict__ out) {
    __shared__ __align__(16) cf buf[4096];   // exactly 32 KB -> 5 blocks/CU if VGPR <= 96
    const int t = threadIdx.x;
    const int b = blockIdx.x;
    const cf* __restrict__ xr  = (const cf*)x + (size_t)b * 4096;
    const cf* __restrict__ w1c = (const cf*)w1;
    const cf* __restrict__ w2c = (const cf*)w2;
    float sn, cs;

    // ---- pass A: global x*w1 -> fft16 over stride-256 -> twiddle -> LDS ----
    {
        cf v[16];
        #pragma unroll
        for (int q = 0; q < 16; ++q)
            v[q] = pk_cmul(xr[t + 256*q], w1c[t + 256*q]);
        fft16pk(v);
        __sincosf(-TWO_PI * (float)t * (1.0f/4096.0f), &sn, &cs);
        cf w = mkcf(cs, sn);
        buf[SIDX(t)] = v[0];
        cf tw = w;
        #pragma unroll
        for (int p = 1; p < 16; ++p) {
            buf[SIDX(p*256 + t)] = pk_cmul(v[p], tw);
            tw = pk_cmul(tw, w);
        }
    }
    __syncthreads();

    // ---- pass B: within 256-blocks, stride 16, twiddle W_256^jp, in place ----
    {
        const int p    = t >> 4;
        const int jp   = t & 15;
        const int base = p*256 + jp;
        cf u[16];
        #pragma unroll
        for (int q = 0; q < 16; ++q) u[q] = buf[SIDX(base + 16*q)];
        fft16pk(u);
        __sincosf(-TWO_PI * (float)jp * (1.0f/256.0f), &sn, &cs);
        cf w = mkcf(cs, sn);
        buf[SIDX(base)] = u[0];
        cf tw = w;
        #pragma unroll
        for (int pp = 1; pp < 16; ++pp) {
            buf[SIDX(base + 16*pp)] = pk_cmul(u[pp], tw);
            tw = pk_cmul(tw, w);
        }
    }
    __syncthreads();

    // ---- final: incremental F accumulation (low register pressure) ----
    // F[k] = sum_bb K16^{bb*k} * b_k(bb), b_k from z[bb], z[bb+4], z[bb+8], z[bb+12]
    cf F0, F1, F2, F3;
    {
        const cf K1 = mkcf(C1f,-S1f), K2 = mkcf(R2f,-R2f), K3 = mkcf(S1f,-C1f),
                 K6 = mkcf(-R2f,-R2f), K9 = mkcf(-C1f,S1f);
        // batch 1: float4s at offsets 0,4,8,12 -> z{0,1},{4,5},{8,9},{12,13} -> bb=0,1
        f4 q0 = *reinterpret_cast<const f4*>(&buf[SIDX(16*t + 0)]);
        f4 q2 = *reinterpret_cast<const f4*>(&buf[SIDX(16*t + 4)]);
        f4 q4 = *reinterpret_cast<const f4*>(&buf[SIDX(16*t + 8)]);
        f4 q6 = *reinterpret_cast<const f4*>(&buf[SIDX(16*t + 12)]);
        {   // bb = 0: z0, z4, z8, z12
            cf a0 = mkcf(q0.x,q0.y), a1 = mkcf(q2.x,q2.y), a2 = mkcf(q4.x,q4.y), a3 = mkcf(q6.x,q6.y);
            cf s0 = pk_add(a0,a2), d0 = pk_sub(a0,a2);
            cf s1 = pk_add(a1,a3), d1 = pk_sub(a1,a3);
            F0 = pk_add(s0,s1);
            F1 = pk_mi(d0,d1);
            F2 = pk_sub(s0,s1);
            F3 = pk_pi(d0,d1);
        }
        {   // bb = 1: z1, z5, z9, z13 ; K multipliers 1,K1,K2,K3
            cf a0 = mkcf(q0.z,q0.w), a1 = mkcf(q2.z,q2.w), a2 = mkcf(q4.z,q4.w), a3 = mkcf(q6.z,q6.w);
            cf s0 = pk_add(a0,a2), d0 = pk_sub(a0,a2);
            cf s1 = pk_add(a1,a3), d1 = pk_sub(a1,a3);
            F0 = pk_add(F0, pk_add(s0,s1));
            F1 = pk_add(F1, pk_cmuls(pk_mi(d0,d1), K1));
            F2 = pk_add(F2, pk_cmuls(pk_sub(s0,s1), K2));
            F3 = pk_add(F3, pk_cmuls(pk_pi(d0,d1), K3));
        }
        // batch 2: float4s at offsets 2,6,10,14 -> z{2,3},{6,7},{10,11},{14,15} -> bb=2,3
        f4 q1 = *reinterpret_cast<const f4*>(&buf[SIDX(16*t + 2)]);
        f4 q3 = *reinterpret_cast<const f4*>(&buf[SIDX(16*t + 6)]);
        f4 q5 = *reinterpret_cast<const f4*>(&buf[SIDX(16*t + 10)]);
        f4 q7 = *reinterpret_cast<const f4*>(&buf[SIDX(16*t + 14)]);
        {   // bb = 2: z2, z6, z10, z14 ; K multipliers 1,K2,-i,K6
            cf a0 = mkcf(q1.x,q1.y), a1 = mkcf(q3.x,q3.y), a2 = mkcf(q5.x,q5.y), a3 = mkcf(q7.x,q7.y);
            cf s0 = pk_add(a0,a2), d0 = pk_sub(a0,a2);
            cf s1 = pk_add(a1,a3), d1 = pk_sub(a1,a3);
            F0 = pk_add(F0, pk_add(s0,s1));
            F1 = pk_add(F1, pk_cmuls(pk_mi(d0,d1), K2));
            F2 = pk_add(F2, pk_ni(pk_sub(s0,s1)));
            F3 = pk_add(F3, pk_cmuls(pk_pi(d0,d1), K6));
        }
        {   // bb = 3: z3, z7, z11, z15 ; K multipliers 1,K3,K6,K9
            cf a0 = mkcf(q1.z,q1.w), a1 = mkcf(q3.z,q3.w), a2 = mkcf(q5.z,q5.w), a3 = mkcf(q7.z,q7.w);
            cf s0 = pk_add(a0,a2), d0 = pk_sub(a0,a2);
            cf s1 = pk_add(a1,a3), d1 = pk_sub(a1,a3);
            F0 = pk_add(F0, pk_add(s0,s1));
            F1 = pk_add(F1, pk_cmuls(pk_mi(d0,d1), K3));
            F2 = pk_add(F2, pk_cmuls(pk_sub(s0,s1), K6));
            F3 = pk_add(F3, pk_cmuls(pk_pi(d0,d1), K9));
        }
    }
    __syncthreads();   // all buf reads done -> safe to alias sred onto buf

    float rv[10];
    {
        // bin n = 256*p'' + c0, c0 = 16*(t&15) + (t>>4)
        const int c0i = ((t & 15) << 4) | (t >> 4);
        cf Q0 = pk_cmul(relu2(F0), w2c[c0i]);
        cf Q1 = pk_cmul(relu2(F1), w2c[256 + c0i]);
        cf Q2 = pk_cmul(relu2(F2), w2c[512 + c0i]);
        cf Q3 = pk_cmul(relu2(F3), w2c[768 + c0i]);

        cf s0 = pk_add(Q0,Q2), d0 = pk_sub(Q0,Q2);
        cf s1 = pk_add(Q1,Q3), d1 = pk_sub(Q1,Q3);
        cf G0 = pk_add(s0,s1);
        cf G1 = pk_mi(d0,d1);
        cf G2 = pk_sub(s0,s1);
        cf G3 = pk_pi(d0,d1);
        __sincosf(-TWO_PI * (float)c0i * (1.0f/1024.0f), &sn, &cs);
        cf wk = mkcf(cs, sn);
        cf r1 = wk;
        cf a1 = pk_cmul(G1, r1);
        cf r2 = pk_cmul(r1, wk);
        cf a2 = pk_cmul(G2, r2);
        cf r3 = pk_cmul(r2, wk);
        cf a3 = pk_cmul(G3, r3);
        cf r4 = pk_cmul(r3, wk);
        cf a4 = pk_cmul(G0, r4);              // k=4: (-i)^{4p''}=1 -> G0
        rv[0]=G0.x; rv[1]=G0.y; rv[2]=a1.x; rv[3]=a1.y; rv[4]=a2.x;
        rv[5]=a2.y; rv[6]=a3.x; rv[7]=a3.y; rv[8]=a4.x; rv[9]=a4.y;
    }

    // ---- reduce 256 threads -> 10 floats (sred aliased onto buf) ----
    float* sred = (float*)buf;
    #pragma unroll
    for (int i = 0; i < 10; ++i) rv[i] = wred(rv[i]);
    const int lane = t & 63, wv = t >> 6;
    if (lane == 63) {
        #pragma unroll
        for (int i = 0; i < 10; ++i) sred[wv*10 + i] = rv[i];
    }
    __syncthreads();
    if (t < 10) {
        out[b*10 + t] = sred[t] + sred[10+t] + sred[20+t] + sred[30+t];
    }
}

extern "C" void kernel_launch(void* const* d_in, const int* in_sizes, int n_in,
                              void* d_out, int out_size, void* d_ws, size_t ws_size,
                              hipStream_t stream) {
    const float* x  = (const float*)d_in[0];
    const float* w1 = (const float*)d_in[1];
    const float* w2 = (const float*)d_in[2];
    float* out = (float*)d_out;
    fftmlp_pkd<<<NBLK, 256, 0, stream>>>(x, w1, w2, out);
}